// Round 8
// baseline (284.834 us; speedup 1.0000x reference)
//
#include <hip/hip_runtime.h>
#include <hip/hip_bf16.h>

#define N_ROWS 8192
#define DIM    1024
#define NCLS   10240
#define S_SCALE 30.0f
#define M_LARGE 0.4f
#define M_SMALL 0.1f

typedef __attribute__((ext_vector_type(8))) short bf16x8;
typedef __attribute__((ext_vector_type(4))) float f32x4;

__device__ __forceinline__ unsigned short f2bf(float f){
    unsigned int u = __builtin_bit_cast(unsigned int, f);
    unsigned int r = (u + 0x7fffu + ((u >> 16) & 1u)) >> 16;
    return (unsigned short)r;
}

#define GLD16(gp, lp) __builtin_amdgcn_global_load_lds( \
    (const __attribute__((address_space(1))) unsigned int*)(gp), \
    (__attribute__((address_space(3))) unsigned int*)(lp), 16, 0, 0)

// ---------------- prep: inv L2 norms + raw f32->bf16 conversion, zero gsum ----------------
__global__ void prep_kernel(const float* __restrict__ x, const float* __restrict__ w,
                            float* __restrict__ inv_x, float* __restrict__ inv_w,
                            float* __restrict__ gsum,
                            unsigned short* __restrict__ xb, unsigned short* __restrict__ wb){
    int b = blockIdx.x;
    bool isx = (b < N_ROWS);
    int r = isx ? b : b - N_ROWS;
    const float4* src = (const float4*)((isx ? x : w) + (size_t)r * DIM);
    float4 v = src[threadIdx.x];                      // 256 threads * 4 = 1024
    ushort4 pk;
    pk.x = f2bf(v.x); pk.y = f2bf(v.y); pk.z = f2bf(v.z); pk.w = f2bf(v.w);
    ushort4* dst = (ushort4*)((isx ? xb : wb) + (size_t)r * DIM);
    dst[threadIdx.x] = pk;
    float ss = v.x*v.x + v.y*v.y + v.z*v.z + v.w*v.w;
    #pragma unroll
    for (int o = 32; o; o >>= 1) ss += __shfl_down(ss, o);
    __shared__ float part[4];
    int lane = threadIdx.x & 63, wid = threadIdx.x >> 6;
    if (lane == 0) part[wid] = ss;
    __syncthreads();
    if (threadIdx.x == 0){
        float t = part[0] + part[1] + part[2] + part[3];
        float inv = 1.0f / fmaxf(sqrtf(t), 1e-12f);
        if (isx){ inv_x[r] = inv; gsum[r] = 0.0f; }
        else      inv_w[r] = inv;
    }
}

// ---------------- target logit: exact f32 dot x_i . w_label ----------------
__global__ void target_kernel(const float* __restrict__ x, const float* __restrict__ w,
                              const int* __restrict__ labels,
                              const float* __restrict__ inv_x, const float* __restrict__ inv_w,
                              float* __restrict__ tgt){
    int wid = threadIdx.x >> 6, lane = threadIdx.x & 63;
    int i = blockIdx.x * 4 + wid;
    int lab = labels[i];
    const float4* xp = (const float4*)(x + (size_t)i   * DIM);
    const float4* wp = (const float4*)(w + (size_t)lab * DIM);
    float acc = 0.f;
    #pragma unroll
    for (int c = 0; c < 4; ++c){
        float4 a = xp[c*64 + lane];
        float4 b = wp[c*64 + lane];
        acc += a.x*b.x + a.y*b.y + a.z*b.z + a.w*b.w;
    }
    #pragma unroll
    for (int o = 32; o; o >>= 1) acc += __shfl_down(acc, o);
    if (lane == 0){
        float c = acc * inv_x[i] * inv_w[lab];
        c = fminf(fmaxf(c, -1.f), 1.f);
        tgt[i] = c;
    }
}

// ---- fused bf16 GEMM: 256x256 tile, BK=32, ring-4 LDS, counted vmcnt(4) ----
#define BM 256
#define BN 256
#define BK 32
#define NT (DIM/BK)          // 32 K-tiles
#define GRID_X (NCLS/BN)     // 40
#define GRID_Y (N_ROWS/BM)   // 32
#define NWG (GRID_X*GRID_Y)  // 1280, % 8 == 0
#define SLOT (BM*BK)         // 8192 elems = 16 KB per ring slot

__global__ __launch_bounds__(512, 1) void gemm_kernel(
        const unsigned short* __restrict__ xb, const unsigned short* __restrict__ wb,
        const float* __restrict__ inv_x, const float* __restrict__ inv_w,
        float* __restrict__ gsum){
    __shared__ __align__(16) unsigned short As[4][SLOT];   // 64 KB
    __shared__ __align__(16) unsigned short Bs[4][SLOT];   // 64 KB
    __shared__ float sumrow[BM];

    int tid = threadIdx.x;
    int bid = blockIdx.x;
    // bijective XCD swizzle
    int swz = (bid & 7) * (NWG/8) + (bid >> 3);
    int by = swz / GRID_X, bx = swz % GRID_X;
    int row0 = by * BM, col0 = bx * BN;
    int wid = tid >> 6, lane = tid & 63;
    int wm = wid >> 2, wn = wid & 3;           // 2M x 4N waves; wave owns 128x64
    int g = lane >> 4, l16 = lane & 15;

    if (tid < BM) sumrow[tid] = 0.f;

    // staging: one GLD16 = 512 thr x 16B = 8 KB = 128 rows x 32 cols
    int lrow = tid >> 2;                       // 0..127
    int csrc = (tid & 3) ^ (lrow & 3);         // pre-swizzled source chunk
    const unsigned short* gA = xb + (size_t)(row0 + lrow) * DIM + csrc * 8;
    const unsigned short* gB = wb + (size_t)(col0 + lrow) * DIM + csrc * 8;
    int ldso = lrow * BK + (tid & 3) * 8;      // linear LDS dest (elements)

    f32x4 acc[8][4] = {};

    // prologue: stage tiles 0 and 1
    GLD16(gA,                    &As[0][ldso]);
    GLD16(gA + (size_t)128*DIM,  &As[0][128*BK + ldso]);
    GLD16(gB,                    &Bs[0][ldso]);
    GLD16(gB + (size_t)128*DIM,  &Bs[0][128*BK + ldso]);
    GLD16(gA + BK,                    &As[1][ldso]);
    GLD16(gA + BK + (size_t)128*DIM,  &As[1][128*BK + ldso]);
    GLD16(gB + BK,                    &Bs[1][ldso]);
    GLD16(gB + BK + (size_t)128*DIM,  &Bs[1][128*BK + ldso]);
    asm volatile("s_waitcnt vmcnt(4)" ::: "memory");   // tile 0 ready, tile 1 in flight
    __builtin_amdgcn_s_barrier();

    for (int kt = 0; kt < NT; ++kt){
        int s = kt & 3;
        bool pre = (kt + 2 < NT);
        int s2 = (kt + 2) & 3;
        int kof = (kt + 2) * BK;

        bf16x8 af[4], bfv[4];

        // stage A of tile kt+2 (slot retired at tile kt-2)
        if (pre){
            GLD16(gA + kof,                    &As[s2][ldso]);
            GLD16(gA + kof + (size_t)128*DIM,  &As[s2][128*BK + ldso]);
        }

        // ---- P0: read A m0-3 + B n0-3 ; MFMA quadrant m0-3
        #pragma unroll
        for (int m = 0; m < 4; ++m){
            int r = wm*128 + m*16 + l16;
            af[m] = *(const bf16x8*)&As[s][r*BK + ((g ^ (r & 3)) << 3)];
        }
        #pragma unroll
        for (int n = 0; n < 4; ++n){
            int r = wn*64 + n*16 + l16;
            bfv[n] = *(const bf16x8*)&Bs[s][r*BK + ((g ^ (r & 3)) << 3)];
        }
        if (pre){
            GLD16(gB + kof,                    &Bs[s2][ldso]);
            GLD16(gB + kof + (size_t)128*DIM,  &Bs[s2][128*BK + ldso]);
        }
        __builtin_amdgcn_s_barrier();
        asm volatile("s_waitcnt lgkmcnt(0)" ::: "memory");
        __builtin_amdgcn_sched_barrier(0);
        __builtin_amdgcn_s_setprio(1);
        #pragma unroll
        for (int m = 0; m < 4; ++m)
            #pragma unroll
            for (int n = 0; n < 4; ++n)
                acc[m][n] = __builtin_amdgcn_mfma_f32_16x16x32_bf16(af[m], bfv[n], acc[m][n], 0, 0, 0);
        __builtin_amdgcn_s_setprio(0);
        __builtin_amdgcn_s_barrier();

        // ---- P1: read A m4-7 ; MFMA quadrant m4-7 (reuse B regs)
        #pragma unroll
        for (int m = 0; m < 4; ++m){
            int r = wm*128 + (m+4)*16 + l16;
            af[m] = *(const bf16x8*)&As[s][r*BK + ((g ^ (r & 3)) << 3)];
        }
        __builtin_amdgcn_s_barrier();
        asm volatile("s_waitcnt lgkmcnt(0)" ::: "memory");
        __builtin_amdgcn_sched_barrier(0);
        __builtin_amdgcn_s_setprio(1);
        #pragma unroll
        for (int m = 0; m < 4; ++m)
            #pragma unroll
            for (int n = 0; n < 4; ++n)
                acc[m+4][n] = __builtin_amdgcn_mfma_f32_16x16x32_bf16(af[m], bfv[n], acc[m+4][n], 0, 0, 0);
        __builtin_amdgcn_s_setprio(0);

        // ---- boundary: confirm tile kt+1 (issued a full tile ago); keep
        // tile kt+2's 4 loads in flight — counted, never drain to 0 mid-loop.
        if (pre){ asm volatile("s_waitcnt vmcnt(4)" ::: "memory"); }
        else    { asm volatile("s_waitcnt vmcnt(0)" ::: "memory"); }
        __builtin_amdgcn_sched_barrier(0);
        __builtin_amdgcn_s_barrier();
    }

    // epilogue: scale by inv_x[i]*inv_w[j], clamp, exp(S*.), row-sum
    float iw[4];
    #pragma unroll
    for (int n = 0; n < 4; ++n) iw[n] = inv_w[col0 + wn*64 + n*16 + l16];
    #pragma unroll
    for (int m = 0; m < 8; ++m){
        #pragma unroll
        for (int rg = 0; rg < 4; ++rg){
            int rl = wm*128 + m*16 + g*4 + rg;       // local row of this value
            float ix = inv_x[row0 + rl];
            float v = 0.f;
            #pragma unroll
            for (int n = 0; n < 4; ++n){
                float c = acc[m][n][rg] * ix * iw[n];
                c = fminf(fmaxf(c, -1.f), 1.f);
                v += __expf(S_SCALE * c);
            }
            v += __shfl_xor(v, 1);
            v += __shfl_xor(v, 2);
            v += __shfl_xor(v, 4);
            v += __shfl_xor(v, 8);
            if (l16 == 0) atomicAdd(&sumrow[rl], v);
        }
    }
    __syncthreads();
    if (tid < BM) atomicAdd(&gsum[row0 + tid], sumrow[tid]);
}

// ---------------- finalize: per-row loss, mean ----------------
__global__ void finalize_kernel(const float* __restrict__ tgt, const float* __restrict__ gsum,
                                const int* __restrict__ labels, float* __restrict__ out){
    double local = 0.0;
    for (int i = threadIdx.x; i < N_ROWS; i += 256){
        float tv = tgt[i];
        float m  = (labels[i] <= 5) ? M_LARGE : M_SMALL;
        float numer = S_SCALE * (tv - m);
        float excl  = gsum[i] - __expf(S_SCALE * tv);
        float denom = __expf(numer) + excl;
        float L = numer - logf(denom);
        local += (double)L;
    }
    #pragma unroll
    for (int o = 32; o; o >>= 1) local += __shfl_down(local, o);
    __shared__ double part[4];
    int lane = threadIdx.x & 63, wid = threadIdx.x >> 6;
    if (lane == 0) part[wid] = local;
    __syncthreads();
    if (threadIdx.x == 0){
        double s = part[0] + part[1] + part[2] + part[3];
        out[0] = (float)(-s / (double)N_ROWS);
    }
}

extern "C" void kernel_launch(void* const* d_in, const int* in_sizes, int n_in,
                              void* d_out, int out_size, void* d_ws, size_t ws_size,
                              hipStream_t stream) {
    const float* x      = (const float*)d_in[0];
    const int*   labels = (const int*)  d_in[1];
    const float* w      = (const float*)d_in[2];

    float* ws    = (float*)d_ws;
    float* inv_x = ws;                    // N
    float* inv_w = inv_x + N_ROWS;        // C
    float* tgt   = inv_w + NCLS;          // N
    float* gsum  = tgt   + N_ROWS;        // N
    unsigned short* xb = (unsigned short*)(gsum + N_ROWS);  // N*D bf16
    unsigned short* wb = xb + (size_t)N_ROWS * DIM;         // C*D bf16

    prep_kernel<<<N_ROWS + NCLS, 256, 0, stream>>>(x, w, inv_x, inv_w, gsum, xb, wb);
    target_kernel<<<N_ROWS/4, 256, 0, stream>>>(x, w, labels, inv_x, inv_w, tgt);
    gemm_kernel<<<NWG, 512, 0, stream>>>(xb, wb, inv_x, inv_w, gsum);
    finalize_kernel<<<1, 256, 0, stream>>>(tgt, gsum, labels, (float*)d_out);
}

// Round 9
// 255.517 us; speedup vs baseline: 1.1147x; 1.1147x over previous
//
#include <hip/hip_runtime.h>
#include <hip/hip_bf16.h>

#define N_ROWS 8192
#define DIM    1024
#define NCLS   10240
#define S_SCALE 30.0f
#define M_LARGE 0.4f
#define M_SMALL 0.1f

typedef __attribute__((ext_vector_type(8))) short bf16x8;
typedef __attribute__((ext_vector_type(4))) float f32x4;

__device__ __forceinline__ unsigned short f2bf(float f){
    unsigned int u = __builtin_bit_cast(unsigned int, f);
    unsigned int r = (u + 0x7fffu + ((u >> 16) & 1u)) >> 16;
    return (unsigned short)r;
}

#define GLD16(gp, lp) __builtin_amdgcn_global_load_lds( \
    (const __attribute__((address_space(1))) unsigned int*)(gp), \
    (__attribute__((address_space(3))) unsigned int*)(lp), 16, 0, 0)

// ---------------- prep: inv L2 norms + raw f32->bf16 conversion, zero gsum ----------------
__global__ void prep_kernel(const float* __restrict__ x, const float* __restrict__ w,
                            float* __restrict__ inv_x, float* __restrict__ inv_w,
                            float* __restrict__ gsum,
                            unsigned short* __restrict__ xb, unsigned short* __restrict__ wb){
    int b = blockIdx.x;
    bool isx = (b < N_ROWS);
    int r = isx ? b : b - N_ROWS;
    const float4* src = (const float4*)((isx ? x : w) + (size_t)r * DIM);
    float4 v = src[threadIdx.x];                      // 256 threads * 4 = 1024
    ushort4 pk;
    pk.x = f2bf(v.x); pk.y = f2bf(v.y); pk.z = f2bf(v.z); pk.w = f2bf(v.w);
    ushort4* dst = (ushort4*)((isx ? xb : wb) + (size_t)r * DIM);
    dst[threadIdx.x] = pk;
    float ss = v.x*v.x + v.y*v.y + v.z*v.z + v.w*v.w;
    #pragma unroll
    for (int o = 32; o; o >>= 1) ss += __shfl_down(ss, o);
    __shared__ float part[4];
    int lane = threadIdx.x & 63, wid = threadIdx.x >> 6;
    if (lane == 0) part[wid] = ss;
    __syncthreads();
    if (threadIdx.x == 0){
        float t = part[0] + part[1] + part[2] + part[3];
        float inv = 1.0f / fmaxf(sqrtf(t), 1e-12f);
        if (isx){ inv_x[r] = inv; gsum[r] = 0.0f; }
        else      inv_w[r] = inv;
    }
}

// ---------------- target logit: exact f32 dot x_i . w_label ----------------
__global__ void target_kernel(const float* __restrict__ x, const float* __restrict__ w,
                              const int* __restrict__ labels,
                              const float* __restrict__ inv_x, const float* __restrict__ inv_w,
                              float* __restrict__ tgt){
    int wid = threadIdx.x >> 6, lane = threadIdx.x & 63;
    int i = blockIdx.x * 4 + wid;
    int lab = labels[i];
    const float4* xp = (const float4*)(x + (size_t)i   * DIM);
    const float4* wp = (const float4*)(w + (size_t)lab * DIM);
    float acc = 0.f;
    #pragma unroll
    for (int c = 0; c < 4; ++c){
        float4 a = xp[c*64 + lane];
        float4 b = wp[c*64 + lane];
        acc += a.x*b.x + a.y*b.y + a.z*b.z + a.w*b.w;
    }
    #pragma unroll
    for (int o = 32; o; o >>= 1) acc += __shfl_down(acc, o);
    if (lane == 0){
        float c = acc * inv_x[i] * inv_w[lab];
        c = fminf(fmaxf(c, -1.f), 1.f);
        tgt[i] = c;
    }
}

// ---- fused bf16 GEMM: 256x256, BK=64, 8-phase/2-Ktile iter, counted vmcnt ----
#define BM 256
#define BN 256
#define BK 64
#define NT (DIM/BK)          // 16 K-tiles -> 8 iterations
#define GRID_X (NCLS/BN)     // 40
#define GRID_Y (N_ROWS/BM)   // 32
#define NWG (GRID_X*GRID_Y)  // 1280, % 8 == 0

// stage one half-tile (128 rows) = 2 x GLD16 (each 512thr x 16B = 64 rows)
#define STAGE_A(D, H, KO) { \
    GLD16(gA + (size_t)((H)*128)*DIM + (KO),    &As[D][((H)*128)*BK + ldso]); \
    GLD16(gA + (size_t)((H)*128+64)*DIM + (KO), &As[D][((H)*128+64)*BK + ldso]); }
#define STAGE_B(D, H, KO) { \
    GLD16(gB + (size_t)((H)*128)*DIM + (KO),    &Bs[D][((H)*128)*BK + ldso]); \
    GLD16(gB + (size_t)((H)*128+64)*DIM + (KO), &Bs[D][((H)*128+64)*BK + ldso]); }

// proven conflict-free fragment reads: 128B rows, chunk XOR over 8 chunks
#define RD_A(BUF, MH, KK) \
    _Pragma("unroll") for (int m = 0; m < 4; ++m){ \
        int r = wm*128 + ((MH)*4+m)*16 + l16; \
        af[m] = *(const bf16x8*)&As[BUF][r*BK + ((((KK)*4+g) ^ (r & 7)) << 3)]; }
#define RD_B(BUF, KK) \
    _Pragma("unroll") for (int n = 0; n < 4; ++n){ \
        int r = wn*64 + n*16 + l16; \
        bfv[n] = *(const bf16x8*)&Bs[BUF][r*BK + ((((KK)*4+g) ^ (r & 7)) << 3)]; }

#define DO_MFMA(MH) \
    _Pragma("unroll") for (int m = 0; m < 4; ++m) \
        _Pragma("unroll") for (int n = 0; n < 4; ++n) \
            acc[(MH)*4+m][n] = __builtin_amdgcn_mfma_f32_16x16x32_bf16(af[m], bfv[n], acc[(MH)*4+m][n], 0, 0, 0);

#define PH_PRE \
    __builtin_amdgcn_s_barrier(); \
    asm volatile("s_waitcnt lgkmcnt(0)" ::: "memory"); \
    __builtin_amdgcn_sched_barrier(0); \
    __builtin_amdgcn_s_setprio(1);
#define PH_POST \
    __builtin_amdgcn_s_setprio(0); \
    __builtin_amdgcn_s_barrier();

__global__ __launch_bounds__(512, 1) void gemm_kernel(
        const unsigned short* __restrict__ xb, const unsigned short* __restrict__ wb,
        const float* __restrict__ inv_x, const float* __restrict__ inv_w,
        float* __restrict__ gsum){
    __shared__ __align__(16) unsigned short As[2][BM*BK];   // 2 x 32 KB
    __shared__ __align__(16) unsigned short Bs[2][BN*BK];   // 2 x 32 KB
    __shared__ float sumrow[BM];

    int tid = threadIdx.x;
    int bid = blockIdx.x;
    // bijective XCD swizzle
    int swz = (bid & 7) * (NWG/8) + (bid >> 3);
    int by = swz / GRID_X, bx = swz % GRID_X;
    int row0 = by * BM, col0 = bx * BN;
    int wid = tid >> 6, lane = tid & 63;
    int wm = wid >> 2, wn = wid & 3;           // 2M x 4N waves; wave owns 128x64
    int g = lane >> 4, l16 = lane & 15;

    if (tid < BM) sumrow[tid] = 0.f;

    // staging geometry: one GLD16 = 512 thr x 16B = 64 rows x 64 cols
    int srow = tid >> 3;                       // 0..63
    int csrc = (tid & 7) ^ (srow & 7);         // pre-swizzled source chunk
    const unsigned short* gA = xb + (size_t)(row0 + srow) * DIM + csrc * 8;
    const unsigned short* gB = wb + (size_t)(col0 + srow) * DIM + csrc * 8;
    int ldso = srow * BK + (tid & 7) * 8;      // linear LDS dest (elements)

    f32x4 acc[8][4] = {};

    // prologue: A(0),B(0) -> buf0 ; B(1) -> buf1 (A(1) staged in-loop ph0/ph1)
    STAGE_A(0, 0, 0); STAGE_A(0, 1, 0);
    STAGE_B(0, 0, 0); STAGE_B(0, 1, 0);
    STAGE_B(1, 0, BK); STAGE_B(1, 1, BK);
    asm volatile("s_waitcnt vmcnt(4)" ::: "memory");   // A(0),B(0) ready; B(1) in flight
    __builtin_amdgcn_s_barrier();

    for (int i = 0; i < NT/2; ++i){
        int t = 2*i;
        const bool g2 = (i < NT/2 - 1);         // t+2 / t+3 valid
        int k1o = (t+1)*BK, k2o = (t+2)*BK, k3o = (t+3)*BK;
        bf16x8 af[4], bfv[4];

        // ph0: tile t k0 m0-3 (+B) ; stage A-h0(t+1)->As[1]  [As[1] dead since prev ph7]
        RD_A(0, 0, 0); RD_B(0, 0);
        STAGE_A(1, 0, k1o);
        PH_PRE  DO_MFMA(0)  PH_POST

        // ph1: tile t k0 m4-7 ; stage A-h1(t+1)->As[1]
        RD_A(0, 1, 0);
        STAGE_A(1, 1, k1o);
        PH_PRE  DO_MFMA(1)  PH_POST

        // ph2: tile t k1 m0-3 (+B) ; no stage  [Bs[0] dead after this phase]
        RD_A(0, 0, 1); RD_B(0, 1);
        PH_PRE  DO_MFMA(0)  PH_POST

        // ph3: tile t k1 m4-7 ; stage B-h0(t+2)->Bs[0] ; counted wait
        RD_A(0, 1, 1);
        if (g2) STAGE_B(0, 0, k2o);
        PH_PRE  DO_MFMA(1)
        __builtin_amdgcn_s_setprio(0);
        // retire B(t+1)[4]+A(t+1)[4], keep B-h0(t+2)[2] in flight
        if (g2){ asm volatile("s_waitcnt vmcnt(2)" ::: "memory"); }
        else   { asm volatile("s_waitcnt vmcnt(0)" ::: "memory"); }
        __builtin_amdgcn_sched_barrier(0);
        __builtin_amdgcn_s_barrier();

        // ph4: tile t+1 k0 m0-3 (+B) ; stage B-h1(t+2)->Bs[0]
        RD_A(1, 0, 0); RD_B(1, 0);
        if (g2) STAGE_B(0, 1, k2o);
        PH_PRE  DO_MFMA(0)  PH_POST

        // ph5: tile t+1 k0 m4-7 ; stage A-h0(t+2)->As[0]  [As[0] dead after ph3]
        RD_A(1, 1, 0);
        if (g2) STAGE_A(0, 0, k2o);
        PH_PRE  DO_MFMA(1)  PH_POST

        // ph6: tile t+1 k1 m0-3 (+B) ; stage A-h1(t+2)->As[0]
        RD_A(1, 0, 1); RD_B(1, 1);
        if (g2) STAGE_A(0, 1, k2o);
        PH_PRE  DO_MFMA(0)  PH_POST

        // ph7: tile t+1 k1 m4-7 ; stage B(t+3) both halves->Bs[1] ; counted wait
        RD_A(1, 1, 1);
        if (g2){ STAGE_B(1, 0, k3o); STAGE_B(1, 1, k3o); }
        PH_PRE  DO_MFMA(1)
        __builtin_amdgcn_s_setprio(0);
        // retire B(t+2)[4]+A(t+2)[4], keep B(t+3)[4] in flight
        asm volatile("s_waitcnt vmcnt(4)" ::: "memory");
        __builtin_amdgcn_sched_barrier(0);
        __builtin_amdgcn_s_barrier();
    }

    // epilogue: scale by inv_x[i]*inv_w[j], clamp, exp(S*.), row-sum
    float iw[4];
    #pragma unroll
    for (int n = 0; n < 4; ++n) iw[n] = inv_w[col0 + wn*64 + n*16 + l16];
    #pragma unroll
    for (int m = 0; m < 8; ++m){
        #pragma unroll
        for (int rg = 0; rg < 4; ++rg){
            int rl = wm*128 + m*16 + g*4 + rg;       // local row of this value
            float ix = inv_x[row0 + rl];
            float v = 0.f;
            #pragma unroll
            for (int n = 0; n < 4; ++n){
                float c = acc[m][n][rg] * ix * iw[n];
                c = fminf(fmaxf(c, -1.f), 1.f);
                v += __expf(S_SCALE * c);
            }
            v += __shfl_xor(v, 1);
            v += __shfl_xor(v, 2);
            v += __shfl_xor(v, 4);
            v += __shfl_xor(v, 8);
            if (l16 == 0) atomicAdd(&sumrow[rl], v);
        }
    }
    __syncthreads();
    if (tid < BM) atomicAdd(&gsum[row0 + tid], sumrow[tid]);
}

// ---------------- finalize: per-row loss, mean ----------------
__global__ void finalize_kernel(const float* __restrict__ tgt, const float* __restrict__ gsum,
                                const int* __restrict__ labels, float* __restrict__ out){
    double local = 0.0;
    for (int i = threadIdx.x; i < N_ROWS; i += 256){
        float tv = tgt[i];
        float m  = (labels[i] <= 5) ? M_LARGE : M_SMALL;
        float numer = S_SCALE * (tv - m);
        float excl  = gsum[i] - __expf(S_SCALE * tv);
        float denom = __expf(numer) + excl;
        float L = numer - logf(denom);
        local += (double)L;
    }
    #pragma unroll
    for (int o = 32; o; o >>= 1) local += __shfl_down(local, o);
    __shared__ double part[4];
    int lane = threadIdx.x & 63, wid = threadIdx.x >> 6;
    if (lane == 0) part[wid] = local;
    __syncthreads();
    if (threadIdx.x == 0){
        double s = part[0] + part[1] + part[2] + part[3];
        out[0] = (float)(-s / (double)N_ROWS);
    }
}

extern "C" void kernel_launch(void* const* d_in, const int* in_sizes, int n_in,
                              void* d_out, int out_size, void* d_ws, size_t ws_size,
                              hipStream_t stream) {
    const float* x      = (const float*)d_in[0];
    const int*   labels = (const int*)  d_in[1];
    const float* w      = (const float*)d_in[2];

    float* ws    = (float*)d_ws;
    float* inv_x = ws;                    // N
    float* inv_w = inv_x + N_ROWS;        // C
    float* tgt   = inv_w + NCLS;          // N
    float* gsum  = tgt   + N_ROWS;        // N
    unsigned short* xb = (unsigned short*)(gsum + N_ROWS);  // N*D bf16
    unsigned short* wb = xb + (size_t)N_ROWS * DIM;         // C*D bf16

    prep_kernel<<<N_ROWS + NCLS, 256, 0, stream>>>(x, w, inv_x, inv_w, gsum, xb, wb);
    target_kernel<<<N_ROWS/4, 256, 0, stream>>>(x, w, labels, inv_x, inv_w, tgt);
    gemm_kernel<<<NWG, 512, 0, stream>>>(xb, wb, inv_x, inv_w, gsum);
    finalize_kernel<<<1, 256, 0, stream>>>(tgt, gsum, labels, (float*)d_out);
}